// Round 5
// baseline (5323.718 us; speedup 1.0000x reference)
//
#include <hip/hip_runtime.h>

#define T_   256
#define HID_ 1024
#define D2   512

typedef __attribute__((ext_vector_type(8))) short  short8;
typedef __attribute__((ext_vector_type(8))) __bf16 bf16x8;
typedef __attribute__((ext_vector_type(4))) float  f32x4;
typedef unsigned long long ull;

__device__ __forceinline__ float sigmoidf_(float x) {
    return __fdividef(1.0f, 1.0f + __expf(-x));
}
__device__ __forceinline__ float tanhf_(float x) {
    return 1.0f - __fdividef(2.0f, 1.0f + __expf(2.0f * x));
}
__device__ __forceinline__ unsigned short bf16hi(float x) {
    unsigned u = __float_as_uint(x);
    return (unsigned short)((u + 0x7FFFu + ((u >> 16) & 1u)) >> 16);
}
__device__ __forceinline__ float bf2f(unsigned short h) {
    return __uint_as_float((unsigned)h << 16);
}
__device__ __forceinline__ f32x4 mfma_(short8 a, short8 b, f32x4 c) {
    union { short8 s; bf16x8 b; } ua, ub;
    ua.s = a; ub.s = b;
    return __builtin_amdgcn_mfma_f32_16x16x32_bf16(ua.b, ub.b, c, 0, 0, 0);
}
// coherent 16B load as two compiler-tracked 8B system-scope relaxed atomics
// (emits global_load_dwordx2 sc0 sc1; compiler inserts correct vmcnt per use)
__device__ __forceinline__ short8 cohLoad16(const unsigned short* p) {
    union { short8 s; ull u[2]; } r;
    r.u[0] = __hip_atomic_load((const ull*)p,     __ATOMIC_RELAXED, __HIP_MEMORY_SCOPE_SYSTEM);
    r.u[1] = __hip_atomic_load((const ull*)p + 1, __ATOMIC_RELAXED, __HIP_MEMORY_SCOPE_SYSTEM);
    return r.s;
}

// ---------------- prelim: W2 = fc2_w @ fc1_w, b2 = fc2_w@fc1_b + fc2_b ----
__global__ __launch_bounds__(256) void k_w2(
    const float* __restrict__ fc2_w, const float* __restrict__ fc1_w,
    const float* __restrict__ fc1_b, const float* __restrict__ fc2_b,
    float* __restrict__ W2, float* __restrict__ b2)
{
    int idx = blockIdx.x * 256 + threadIdx.x;   // 0..65535
    int r = idx >> 6, c = idx & 63;
    float acc = 0.f;
    for (int k = 0; k < D2; ++k)
        acc += fc2_w[(size_t)r * D2 + k] * fc1_w[(size_t)k * 64 + c];
    W2[idx] = acc;
    if (c == 0) {
        float a = fc2_b[r];
        for (int k = 0; k < D2; ++k)
            a += fc2_w[(size_t)r * D2 + k] * fc1_b[k];
        b2[r] = a;
    }
}

// -------- prelim: Wc = w_ih @ W2 (bf16 split planes), bc = w_ih@b2 + b_ih --
__global__ __launch_bounds__(256) void k_wc(
    const float* __restrict__ w_ih, const float* __restrict__ W2,
    const float* __restrict__ b2, const float* __restrict__ b_ih,
    unsigned short* __restrict__ wc_hi, unsigned short* __restrict__ wc_lo,
    float* __restrict__ bc)
{
    int idx = blockIdx.x * 256 + threadIdx.x;   // 0..196607
    int r = idx >> 6, c = idx & 63;
    float acc = 0.f;
    for (int k = 0; k < HID_; ++k)
        acc += w_ih[(size_t)r * HID_ + k] * W2[(size_t)k * 64 + c];
    unsigned short h = bf16hi(acc);
    wc_hi[idx] = h;
    wc_lo[idx] = bf16hi(acc - bf2f(h));
    if (c == 0) {
        float a = b_ih[r];
        for (int k = 0; k < HID_; ++k)
            a += w_ih[(size_t)r * HID_ + k] * b2[k];
        bc[r] = a;
    }
}

// ---------------- prelim: split w_hh into bf16 hi/lo planes ----------------
__global__ __launch_bounds__(256) void k_splitw(
    const float* __restrict__ w, unsigned short* __restrict__ hi,
    unsigned short* __restrict__ lo)
{
    int i4 = (blockIdx.x * 256 + threadIdx.x) * 4;
    float4 v = *(const float4*)(w + i4);
    float vv[4] = {v.x, v.y, v.z, v.w};
    unsigned short h4[4], l4[4];
    #pragma unroll
    for (int i = 0; i < 4; ++i) {
        h4[i] = bf16hi(vv[i]);
        l4[i] = bf16hi(vv[i] - bf2f(h4[i]));
    }
    *(ull*)(hi + i4) =
        (ull)h4[0] | ((ull)h4[1] << 16) | ((ull)h4[2] << 32) | ((ull)h4[3] << 48);
    *(ull*)(lo + i4) =
        (ull)l4[0] | ((ull)l4[1] << 16) | ((ull)l4[2] << 32) | ((ull)l4[3] << 48);
}

// ------- prelim: h0 -> bf16 split planes in fragment-granule layout --------
// ushort elem = (k>>5)*8192 + b*32 + ((k>>3)&3)*8 + (k&7)
__global__ __launch_bounds__(256) void k_split_h0(
    const float* __restrict__ hn, unsigned short* __restrict__ hi,
    unsigned short* __restrict__ lo)
{
    int gid = blockIdx.x * 256 + threadIdx.x;      // 0..32767
    int b = gid >> 7, kseg = gid & 127;
    const float* src = hn + (size_t)b * HID_ + kseg * 8;
    short8 h8, l8;
    #pragma unroll
    for (int i = 0; i < 8; ++i) {
        float v = src[i];
        unsigned short h = bf16hi(v);
        ((short*)&h8)[i] = (short)h;
        ((short*)&l8)[i] = (short)bf16hi(v - bf2f(h));
    }
    size_t off = (size_t)(kseg >> 2) * 8192 + b * 32 + (kseg & 3) * 8;
    *(short8*)(hi + off) = h8;
    *(short8*)(lo + off) = l8;
}

// ---------------- main persistent GRU kernel (barrier-free K-loop) ---------
// 256 blocks x 256 threads (1 block/CU). Block g: ct=g&31 (32 h-cols),
// bt=g>>5 (32 batches); g%8==ct%8 pins each col-group's w_hh slice to one
// XCD L2. Wave wv owns K-quarter [wv*256,(wv+1)*256): B-frags loaded DIRECTLY
// from L2 into regs (no LDS, no barriers in K-loop; each frag read once per
// CU). A-frags (h) via coherent 8B-pair loads, 4-slot prefetch ring. Wc gi
// fragments live in registers for all 256 steps. Per-quarter publish counters
// let each wave start as soon as ITS K-slice of h(t) is coherent. LDS only
// for the 4-way C-partial reduction (strides 100/36: 2-way max, free).
__global__ __launch_bounds__(256, 1) void k_gru(
    const float* __restrict__ input,
    const float* __restrict__ hn,
    const float* __restrict__ b_hh,
    const float* __restrict__ bc,
    const unsigned short* __restrict__ whh_hi,
    const unsigned short* __restrict__ whh_lo,
    const unsigned short* __restrict__ wc_hi,
    const unsigned short* __restrict__ wc_lo,
    unsigned short* __restrict__ hxA_hi, unsigned short* __restrict__ hxA_lo,
    unsigned short* __restrict__ hxB_hi, unsigned short* __restrict__ hxB_lo,
    float* __restrict__ hn_out,
    int* __restrict__ bar)
{
    const int g = blockIdx.x, ct = g & 31, bt = g >> 5;
    const int j0 = ct << 5, b0 = bt << 5;
    const int tid = threadIdx.x, lane = tid & 63, wv = tid >> 6;
    const int l15 = lane & 15, quad = lane >> 4;
    const int mgi = wv >> 1, kcgi = wv & 1;

    __shared__ float smF[15104];   // 4x(32x100) main + 4x(16x36) acci

    // B-frag row offsets (ushort elems into a w_hh plane)
    int bofs[6];
    #pragma unroll
    for (int nt = 0; nt < 6; ++nt) {
        int row = nt * 16 + l15;
        bofs[nt] = ((row >> 5) * 1024 + j0 + (row & 31)) * 1024;
    }
    const int kw = wv * 256 + quad * 8;   // k elem base within row

    // gi Wc fragments: step-invariant -> resident in regs
    short8 gW[6][2];
    #pragma unroll
    for (int nt = 0; nt < 6; ++nt) {
        int row = nt * 16 + l15;
        int co = ((row >> 5) * 1024 + j0 + (row & 31)) * 64 + kcgi * 32 + quad * 8;
        gW[nt][0] = *(const short8*)(wc_hi + co);
        gW[nt][1] = *(const short8*)(wc_lo + co);
    }

    const size_t aoff0 = (size_t)(b0 + l15) * 32 + quad * 8;   // m=0
    const size_t aoff1 = aoff0 + 512;                          // m=1 (+16 batches)
    const float* xrow = input + (size_t)(b0 + mgi * 16 + l15) * (T_ * 64)
                              + kcgi * 32 + quad * 8;

    // gate-phase statics: thread owns (b = b0+gb, j = j0+gj4..+3)
    const int gb = tid >> 3, gj4 = (tid & 7) << 2;
    float hreg[4], br[4], bz[4], bni[4], bnh[4];
    #pragma unroll
    for (int i = 0; i < 4; ++i) {
        int j = j0 + gj4 + i;
        hreg[i] = hn[(size_t)(b0 + gb) * HID_ + j];
        br[i]  = bc[j] + b_hh[j];
        bz[i]  = bc[1024 + j] + b_hh[1024 + j];
        bni[i] = bc[2048 + j];
        bnh[i] = b_hh[2048 + j];
    }
    const size_t hoB = (size_t)ct * 8192 + (size_t)(b0 + gb) * 32 + gj4;

    int* myArr = bar + bt * 128 + (ct >> 3) * 32;  // this block's quarter
    int* wArr  = bar + bt * 128 + wv * 32;         // the quarter this wave consumes

    f32x4 acc[2][6], acci[2];

    #pragma unroll 1
    for (int t = 0; t < 256; ++t) {
        const unsigned short* rdh = (t & 1) ? hxB_hi : hxA_hi;
        const unsigned short* rdl = (t & 1) ? hxB_lo : hxA_lo;
        unsigned short* wrh = (t & 1) ? hxA_hi : hxB_hi;
        unsigned short* wrl = (t & 1) ? hxA_lo : hxB_lo;

        // ---- gi (h-independent, overlaps the coming spin) ----
        float xv[8];
        *(float4*)&xv[0] = *(const float4*)(xrow + (size_t)t * 64);
        *(float4*)&xv[4] = *(const float4*)(xrow + (size_t)t * 64 + 4);
        short8 xh, xl;
        #pragma unroll
        for (int i = 0; i < 8; ++i) {
            unsigned short h = bf16hi(xv[i]);
            ((short*)&xh)[i] = (short)h;
            ((short*)&xl)[i] = (short)bf16hi(xv[i] - bf2f(h));
        }
        #pragma unroll
        for (int m = 0; m < 2; ++m)
            #pragma unroll
            for (int nt = 0; nt < 6; ++nt)
                acc[m][nt] = (f32x4){0.f, 0.f, 0.f, 0.f};
        #pragma unroll
        for (int nt = 0; nt < 4; ++nt) {
            f32x4 v = acc[mgi][nt];
            v = mfma_(xh, gW[nt][0], v);
            v = mfma_(xh, gW[nt][1], v);
            v = mfma_(xl, gW[nt][0], v);
            acc[mgi][nt] = v;
        }
        #pragma unroll
        for (int jn = 0; jn < 2; ++jn) {
            f32x4 v = (f32x4){0.f, 0.f, 0.f, 0.f};
            v = mfma_(xh, gW[4 + jn][0], v);
            v = mfma_(xh, gW[4 + jn][1], v);
            v = mfma_(xl, gW[4 + jn][0], v);
            acci[jn] = v;
        }

        // ---- per-wave spin: this wave's K-quarter of h(t) published ----
        if (t > 0) {
            while (__hip_atomic_load(wArr, __ATOMIC_RELAXED,
                                     __HIP_MEMORY_SCOPE_SYSTEM) < (t << 3))
                __builtin_amdgcn_s_sleep(2);
        }

        // ---- prologue: A slots 0..3 (kc 0..3), B bufs kc 0,1 ----
        short8 A[4][2][2];
        #pragma unroll
        for (int s = 0; s < 4; ++s) {
            size_t cb = (size_t)(wv * 8 + s) * 8192;
            A[s][0][0] = cohLoad16(rdh + cb + aoff0);
            A[s][1][0] = cohLoad16(rdh + cb + aoff1);
            A[s][0][1] = cohLoad16(rdl + cb + aoff0);
            A[s][1][1] = cohLoad16(rdl + cb + aoff1);
        }
        short8 B[2][6][2];
        #pragma unroll
        for (int c = 0; c < 2; ++c)
            #pragma unroll
            for (int nt = 0; nt < 6; ++nt) {
                B[c][nt][0] = *(const short8*)(whh_hi + bofs[nt] + kw + c * 32);
                B[c][nt][1] = *(const short8*)(whh_lo + bofs[nt] + kw + c * 32);
            }

        // ---- gh main loop: 8 K=32 chunks, barrier-free, reg-resident ----
        #pragma unroll
        for (int kc = 0; kc < 8; ++kc) {
            const int ab = kc & 3, bb = kc & 1;
            #pragma unroll
            for (int m = 0; m < 2; ++m)
                #pragma unroll
                for (int nt = 0; nt < 6; ++nt) {
                    f32x4 v = acc[m][nt];
                    v = mfma_(A[ab][m][0], B[bb][nt][0], v);
                    v = mfma_(A[ab][m][0], B[bb][nt][1], v);
                    v = mfma_(A[ab][m][1], B[bb][nt][0], v);
                    acc[m][nt] = v;
                }
            if (kc < 4) {   // A prefetch, 3-iter lead (~850 cyc for L3)
                size_t cb = (size_t)(wv * 8 + kc + 4) * 8192;
                A[ab][0][0] = cohLoad16(rdh + cb + aoff0);
                A[ab][1][0] = cohLoad16(rdh + cb + aoff1);
                A[ab][0][1] = cohLoad16(rdl + cb + aoff0);
                A[ab][1][1] = cohLoad16(rdl + cb + aoff1);
            }
            if (kc < 6) {   // B prefetch, 1-iter lead (~280 cyc for L2)
                #pragma unroll
                for (int nt = 0; nt < 6; ++nt) {
                    B[bb][nt][0] = *(const short8*)(whh_hi + bofs[nt] + kw + (kc + 2) * 32);
                    B[bb][nt][1] = *(const short8*)(whh_lo + bofs[nt] + kw + (kc + 2) * 32);
                }
            }
        }

        // ---- dump partials (stride 100/36: 4*stride = 16 mod 32, 2-way) ----
        {
            float* M = smF + wv * 3200;
            #pragma unroll
            for (int m = 0; m < 2; ++m)
                #pragma unroll
                for (int nt = 0; nt < 6; ++nt)
                    #pragma unroll
                    for (int r = 0; r < 4; ++r)
                        M[(m * 16 + quad * 4 + r) * 100 + nt * 16 + l15] = acc[m][nt][r];
            float* Ai = smF + 12800 + wv * 576;
            #pragma unroll
            for (int jn = 0; jn < 2; ++jn)
                #pragma unroll
                for (int r = 0; r < 4; ++r)
                    Ai[(quad * 4 + r) * 36 + jn * 16 + l15] = acci[jn][r];
        }
        __syncthreads();

        // ---- gates: sum 4 gh partials (+2 gi partials for i_n) ----
        ull pkh = 0, pkl = 0;
        const int wlo = (gb >> 4) << 1;
        #pragma unroll
        for (int i = 0; i < 4; ++i) {
            int cj = gj4 + i;
            float rp = br[i], zp = bz[i], hp = bnh[i];
            #pragma unroll
            for (int u = 0; u < 4; ++u) {
                const float* M = smF + u * 3200 + gb * 100;
                rp += M[cj];
                zp += M[32 + cj];
                hp += M[64 + cj];
            }
            float ip = bni[i]
                + smF[12800 + wlo * 576 + (gb & 15) * 36 + cj]
                + smF[12800 + (wlo + 1) * 576 + (gb & 15) * 36 + cj];
            float rr = sigmoidf_(rp), zz = sigmoidf_(zp);
            float nn = tanhf_(ip + rr * hp);
            float hv = (1.f - zz) * nn + zz * hreg[i];
            hreg[i] = hv;
            unsigned short hh = bf16hi(hv);
            unsigned short hl = bf16hi(hv - bf2f(hh));
            pkh |= (ull)hh << (16 * i);
            pkl |= (ull)hl << (16 * i);
        }
        __hip_atomic_store((ull*)(wrh + hoB), pkh, __ATOMIC_RELAXED,
                           __HIP_MEMORY_SCOPE_SYSTEM);
        __hip_atomic_store((ull*)(wrl + hoB), pkl, __ATOMIC_RELAXED,
                           __HIP_MEMORY_SCOPE_SYSTEM);
        if (t == 255) {
            #pragma unroll
            for (int i = 0; i < 4; ++i)
                hn_out[(size_t)(b0 + gb) * HID_ + j0 + gj4 + i] = hreg[i];
        }
        // __syncthreads emits s_waitcnt vmcnt(0) lgkmcnt(0) before s_barrier:
        // every wave's h-stores are at the coherence point before tid0 adds.
        __syncthreads();
        if (t < 255 && tid == 0)
            __hip_atomic_fetch_add(myArr, 1, __ATOMIC_RELAXED,
                                   __HIP_MEMORY_SCOPE_SYSTEM);
    }
}

// ---------------- fc3: out3 = relu(relu(h) @ fc3_wT + fc3_b) --------------
__global__ __launch_bounds__(256) void k_fc3(
    const float* __restrict__ h, const float* __restrict__ fc3_w,
    const float* __restrict__ fc3_b, float* __restrict__ out3)
{
    const int bt = blockIdx.x >> 3;
    const int dt = blockIdx.x & 7;
    const int b0 = bt << 6;
    const int d0 = dt << 6;
    const int tid = threadIdx.x;
    const int tx = tid & 15, ty = tid >> 4;

    __shared__ float sh_h[64][36];
    __shared__ float sh_w[64][36];

    float acc[4][4] = {};
    const int lr = tid >> 3;
    const int lc = (tid & 7) << 2;

    for (int kk = 0; kk < HID_; kk += 32) {
        #pragma unroll
        for (int p = 0; p < 2; ++p) {
            int row = lr + (p << 5);
            float4 v = *(const float4*)(h + (size_t)(b0 + row) * HID_ + kk + lc);
            v.x = fmaxf(v.x, 0.f); v.y = fmaxf(v.y, 0.f);
            v.z = fmaxf(v.z, 0.f); v.w = fmaxf(v.w, 0.f);
            *(float4*)&sh_h[row][lc] = v;
            *(float4*)&sh_w[row][lc] =
                *(const float4*)(fc3_w + (size_t)(d0 + row) * HID_ + kk + lc);
        }
        __syncthreads();
        #pragma unroll
        for (int k = 0; k < 32; ++k) {
            float hv[4], wv[4];
            #pragma unroll
            for (int i = 0; i < 4; ++i) hv[i] = sh_h[ty + (i << 4)][k];
            #pragma unroll
            for (int q = 0; q < 4; ++q) wv[q] = sh_w[tx + (q << 4)][k];
            #pragma unroll
            for (int i = 0; i < 4; ++i)
                #pragma unroll
                for (int q = 0; q < 4; ++q)
                    acc[i][q] += hv[i] * wv[q];
        }
        __syncthreads();
    }
    #pragma unroll
    for (int i = 0; i < 4; ++i) {
        int b = b0 + ty + (i << 4);
        #pragma unroll
        for (int q = 0; q < 4; ++q) {
            int d = d0 + tx + (q << 4);
            out3[(size_t)b * D2 + d] = fmaxf(acc[i][q] + fc3_b[d], 0.f);
        }
    }
}

// ---------------- heads: params[b,o] = out3[b,:]·heads_w[cid[b],o,:]+b ----
__global__ __launch_bounds__(256) void k_heads(
    const float* __restrict__ out3, const int* __restrict__ cult,
    const float* __restrict__ hw, const float* __restrict__ hb,
    float* __restrict__ params)
{
    int b = blockIdx.x;
    int o = threadIdx.x >> 4;
    int l = threadIdx.x & 15;
    int cid = cult[b];
    const float* w = hw + ((size_t)cid * 16 + o) * D2;
    const float* x = out3 + (size_t)b * D2;
    float acc = 0.f;
    #pragma unroll
    for (int m = 0; m < 8; ++m) {
        int d4 = (l + (m << 4)) << 2;
        float4 xv = *(const float4*)(x + d4);
        float4 wv = *(const float4*)(w + d4);
        acc += xv.x * wv.x + xv.y * wv.y + xv.z * wv.z + xv.w * wv.w;
    }
    #pragma unroll
    for (int s = 1; s < 16; s <<= 1)
        acc += __shfl_xor(acc, s, 16);
    if (l == 0)
        params[(size_t)b * 16 + o] = acc + hb[(size_t)cid * 16 + o];
}

extern "C" void kernel_launch(void* const* d_in, const int* in_sizes, int n_in,
                              void* d_out, int out_size, void* d_ws, size_t ws_size,
                              hipStream_t stream)
{
    const float* input = (const float*)d_in[0];
    const float* hn    = (const float*)d_in[1];
    const int*   cult  = (const int*)d_in[2];
    const float* fc1_w = (const float*)d_in[3];
    const float* fc1_b = (const float*)d_in[4];
    const float* fc2_w = (const float*)d_in[5];
    const float* fc2_b = (const float*)d_in[6];
    const float* w_ih  = (const float*)d_in[7];
    const float* w_hh  = (const float*)d_in[8];
    const float* b_ih  = (const float*)d_in[9];
    const float* b_hh  = (const float*)d_in[10];
    const float* fc3_w = (const float*)d_in[11];
    const float* fc3_b = (const float*)d_in[12];
    const float* hw    = (const float*)d_in[13];
    const float* hb    = (const float*)d_in[14];
    float* out = (float*)d_out;
    float* hn_out = out + 4096;          // params 256*16, then hn 256*1024

    char* ws = (char*)d_ws;
    int*   bar    = (int*)ws;                                   // 4 KB
    float* W2     = (float*)(ws + 4096);                        // 256 KB
    float* b2     = (float*)(ws + 266240);
    float* bc     = (float*)(ws + 270336);
    unsigned short* whh_hi = (unsigned short*)(ws + 282624);    // 6 MB
    unsigned short* whh_lo = (unsigned short*)(ws + 282624 + 6291456);
    unsigned short* wc_hi  = (unsigned short*)(ws + 12865536);
    unsigned short* wc_lo  = (unsigned short*)(ws + 13258752);
    unsigned short* hxA_hi = (unsigned short*)(ws + 13651968);
    unsigned short* hxA_lo = (unsigned short*)(ws + 14176256);
    unsigned short* hxB_hi = (unsigned short*)(ws + 14700544);
    unsigned short* hxB_lo = (unsigned short*)(ws + 15224832);
    float* out3   = (float*)(ws + 15749120);                    // 512 KB

    hipMemsetAsync(bar, 0, 4096, stream);
    k_w2<<<256, 256, 0, stream>>>(fc2_w, fc1_w, fc1_b, fc2_b, W2, b2);
    k_wc<<<768, 256, 0, stream>>>(w_ih, W2, b2, b_ih, wc_hi, wc_lo, bc);
    k_splitw<<<3072, 256, 0, stream>>>(w_hh, whh_hi, whh_lo);
    k_split_h0<<<128, 256, 0, stream>>>(hn, hxA_hi, hxA_lo);
    k_gru<<<256, 256, 0, stream>>>(input, hn, b_hh, bc,
                                   whh_hi, whh_lo, wc_hi, wc_lo,
                                   hxA_hi, hxA_lo, hxB_hi, hxB_lo,
                                   hn_out, bar);
    k_fc3<<<32, 256, 0, stream>>>(hn_out, fc3_w, fc3_b, out3);
    k_heads<<<256, 256, 0, stream>>>(out3, cult, hw, hb, out);
}